// Round 6
// baseline (223.017 us; speedup 1.0000x reference)
//
#include <hip/hip_runtime.h>
#include <hip/hip_bf16.h>

#define BS 2
#define SEQ 2048
#define DIN 1024
#define HID 1024
#define NH 16
#define HD 64
#define M_ROWS (BS*SEQ)
#define NQKV 3072

typedef __attribute__((ext_vector_type(8))) short short8;
typedef __attribute__((ext_vector_type(4))) short short4v;
typedef __attribute__((ext_vector_type(8))) __bf16 bf16x8;
typedef __attribute__((ext_vector_type(4))) float floatx4;

// native cast -> v_cvt_pk_bf16_f32 when paired (RNE)
__device__ __forceinline__ short f2bf(float f) {
  return __builtin_bit_cast(short, (__bf16)f);
}
__device__ __forceinline__ float bf2f(short s) {
  return __uint_as_float(((unsigned)(unsigned short)s) << 16);
}

__device__ __forceinline__ floatx4 mfma16(short8 a, short8 b, floatx4 c) {
  return __builtin_amdgcn_mfma_f32_16x16x32_bf16(
      __builtin_bit_cast(bf16x8, a), __builtin_bit_cast(bf16x8, b), c, 0, 0, 0);
}

__device__ __forceinline__ float exp2fast(float x) {
#if __has_builtin(__builtin_amdgcn_exp2f)
  return __builtin_amdgcn_exp2f(x);
#else
  return exp2f(x);
#endif
}

__device__ __forceinline__ void gload_lds16(const void* g, void* l) {
  __builtin_amdgcn_global_load_lds(
      (const __attribute__((address_space(1))) unsigned int*)g,
      (__attribute__((address_space(3))) unsigned int*)l, 16, 0, 0);
}

// ---------- pre-pass: x fp32 -> bf16 ----------
__global__ __launch_bounds__(256) void convx_kernel(const float* __restrict__ x,
                                                    short* __restrict__ xb) {
  int gid = blockIdx.x * 256 + threadIdx.x;
  const float4* x4 = (const float4*)x;
  float4 v0 = x4[2 * gid], v1 = x4[2 * gid + 1];
  short8 o;
  o[0] = f2bf(v0.x); o[1] = f2bf(v0.y); o[2] = f2bf(v0.z); o[3] = f2bf(v0.w);
  o[4] = f2bf(v1.x); o[5] = f2bf(v1.y); o[6] = f2bf(v1.z); o[7] = f2bf(v1.w);
  *(short8*)&xb[(size_t)gid * 8] = o;
}

// ---------- pre-pass: W [K][N] fp32 -> Wt [N][K] bf16 ----------
__global__ __launch_bounds__(256) void transw_kernel(
    const float* __restrict__ Wq, const float* __restrict__ Wk,
    const float* __restrict__ Wv, const float* __restrict__ Wmix,
    short* __restrict__ Wt, short* __restrict__ Wmixt)
{
  __shared__ float Ws[64][65];
  const float* src; short* dst;
  switch (blockIdx.z) {
    case 0:  src = Wq;   dst = Wt;                 break;
    case 1:  src = Wk;   dst = Wt + (1u << 20);    break;
    case 2:  src = Wv;   dst = Wt + (2u << 20);    break;
    default: src = Wmix; dst = Wmixt;              break;
  }
  const int n0 = blockIdx.x * 64, k0 = blockIdx.y * 64;
  const int c = threadIdx.x & 63, r0 = threadIdx.x >> 6;
  #pragma unroll
  for (int i = 0; i < 16; ++i) {
    int rr = r0 + 4 * i;
    Ws[rr][c] = src[(size_t)(k0 + rr) * DIN + n0 + c];
  }
  __syncthreads();
  #pragma unroll
  for (int i = 0; i < 16; ++i) {
    int cc = r0 + 4 * i;
    dst[(size_t)(n0 + cc) * DIN + k0 + c] = f2bf(Ws[c][cc]);
  }
}

// ---------- GEMM: C[M][N] = A[M][K]bf16 @ Bt[N][K]bf16^T + bias ----------
template<int BM, int BN, bool OUT_F32, bool QKV>
__global__ __launch_bounds__(256) void gemm_kernel(
    const short* __restrict__ A, const short* __restrict__ Bt,
    const float* __restrict__ bias, void* __restrict__ Cp,
    short* __restrict__ vt, int Ndim, int Kdim)
{
  constexpr int MT = BM / 32, NT = BN / 32;
  __shared__ short As[BM * 32];
  __shared__ short Bs[BN * 32];
  const int tid = threadIdx.x;
  const int wid = tid >> 6, lane = tid & 63, lg = lane >> 4, lm = lane & 15;
  const int wr = wid >> 1, wc = wid & 1;
  const int m0 = blockIdx.y * BM, n0 = blockIdx.x * BN;

  floatx4 acc[MT][NT];
  #pragma unroll
  for (int i = 0; i < MT; ++i)
    #pragma unroll
    for (int j = 0; j < NT; ++j) acc[i][j] = floatx4{0.f, 0.f, 0.f, 0.f};

  for (int k0 = 0; k0 < Kdim; k0 += 32) {
    __syncthreads();
    #pragma unroll
    for (int j = 0; j < BM / 64; ++j) {
      int flat = tid + 256 * j;
      int row = flat >> 2, ch = (flat & 3) ^ ((row >> 1) & 3);
      gload_lds16(A + (size_t)(m0 + row) * Kdim + k0 + ch * 8,
                  (char*)As + wid * 1024 + j * 4096);
    }
    #pragma unroll
    for (int j = 0; j < BN / 64; ++j) {
      int flat = tid + 256 * j;
      int row = flat >> 2, ch = (flat & 3) ^ ((row >> 1) & 3);
      gload_lds16(Bt + (size_t)(n0 + row) * Kdim + k0 + ch * 8,
                  (char*)Bs + wid * 1024 + j * 4096);
    }
    __syncthreads();

    short8 a[MT], b[NT];
    #pragma unroll
    for (int mt = 0; mt < MT; ++mt) {
      int row = wr * (BM / 2) + mt * 16 + lm;
      a[mt] = *(const short8*)&As[row * 32 + (lg ^ ((row >> 1) & 3)) * 8];
    }
    #pragma unroll
    for (int nt = 0; nt < NT; ++nt) {
      int row = wc * (BN / 2) + nt * 16 + lm;
      b[nt] = *(const short8*)&Bs[row * 32 + (lg ^ ((row >> 1) & 3)) * 8];
    }
    #pragma unroll
    for (int mt = 0; mt < MT; ++mt)
      #pragma unroll
      for (int nt = 0; nt < NT; ++nt)
        acc[mt][nt] = mfma16(a[mt], b[nt], acc[mt][nt]);
  }

  #pragma unroll
  for (int mt = 0; mt < MT; ++mt) {
    const int row0 = m0 + wr * (BM / 2) + mt * 16 + 4 * lg;
    #pragma unroll
    for (int nt = 0; nt < NT; ++nt) {
      const int col = n0 + wc * (BN / 2) + nt * 16 + lm;
      const float bv = bias[col];
      if (QKV && n0 >= 2048) {
        int hd = col - 2048;
        int bb = row0 >> 11, s = row0 & 2047;
        short4v pv;
        #pragma unroll
        for (int r = 0; r < 4; ++r) pv[r] = f2bf(acc[mt][nt][r] + bv);
        *(short4v*)&vt[((size_t)(bb * (NH * HD) + hd)) * SEQ + s] = pv;
      } else {
        #pragma unroll
        for (int r = 0; r < 4; ++r) {
          float v = acc[mt][nt][r] + bv;
          if (OUT_F32) ((float*)Cp)[(size_t)(row0 + r) * Ndim + col] = v;
          else         ((short*)Cp)[(size_t)(row0 + r) * Ndim + col] = f2bf(v);
        }
      }
    }
  }
}

// ---------- split-KV flash attention, direct-global frags, barrier-free ----------
// 1D grid 4608 = 8 xcd * 576; bh pinned to XCD (dispatch round-robin heuristic).
__global__ __launch_bounds__(256, 4) void attn_kernel(
    const short* __restrict__ qkv, const short* __restrict__ vt,
    short* __restrict__ att, short* __restrict__ pO, float* __restrict__ pml)
{
  __shared__ short Ps[4 * 16 * 72];   // per-wave P^T strip [q][kv], stride 72
  const int tid = threadIdx.x;
  const int wid = tid >> 6, lane = tid & 63, lg = lane >> 4, lm = lane & 15;

  // bh -> XCD pinning: hardware round-robins wg id across 8 XCDs
  const int raw = blockIdx.x;
  const int xcd = raw & 7, slot = raw >> 3;        // slot 0..575
  const int bh = xcd + 8 * (slot / 144);
  int id = slot % 144, x, c;
  if (id < 4)        { x = id;                       c = 0;        }
  else if (id < 12)  { int t = id - 4;   x = 4  + (t >> 1); c = t & 1; }
  else if (id < 24)  { int t = id - 12;  x = 8  + t / 3;    c = t % 3; }
  else if (id < 40)  { int t = id - 24;  x = 12 + (t >> 2); c = t & 3; }
  else if (id < 60)  { int t = id - 40;  x = 16 + t / 5;    c = t % 5; }
  else if (id < 84)  { int t = id - 60;  x = 20 + t / 6;    c = t % 6; }
  else if (id < 112) { int t = id - 84;  x = 24 + t / 7;    c = t % 7; }
  else               { int t = id - 112; x = 28 + (t >> 3); c = t & 7; }
  const int nch = (x >> 2) + 1;
  const int tb = c * 4;
  const int te = min(tb + 4, x + 1);
  const int q0 = x * 64;
  const int b = bh >> 4, h = bh & 15;
  const short* qp = qkv + (size_t)(b * SEQ) * NQKV + h * HD;
  const short* kp = qp + HID;
  const short* vp = vt + (size_t)bh * HD * SEQ;

  // Q fragments (B-operand), pre-scaled by log2(e)/sqrt(D); q-row = q0+wid*16+lm
  const float cl2 = 0.18033688011112042f;
  const int qrow_g = q0 + wid * 16 + lm;
  short8 qf[2];
  {
    const short* qrow = qp + (size_t)qrow_g * NQKV;
    #pragma unroll
    for (int kk = 0; kk < 2; ++kk) {
      short8 raw8 = *(const short8*)(qrow + kk * 32 + lg * 8);
      #pragma unroll
      for (int j = 0; j < 8; ++j) qf[kk][j] = f2bf(bf2f(raw8[j]) * cl2);
    }
  }

  short* psw = Ps + wid * 16 * 72;
  float mrow = -3e38f, lrow = 0.f;
  floatx4 o[4];   // O^T: o[nt][r] = O[d = nt*16+4lg+r][q = lm]
  #pragma unroll
  for (int nt = 0; nt < 4; ++nt) o[nt] = floatx4{0.f, 0.f, 0.f, 0.f};

  // per-lane base pointers for direct frag loads
  const short* kfp = kp + (size_t)lm * NQKV + lg * 8;   // + kv*NQKV + kk*32
  const short* vfp = vp + (size_t)lm * SEQ + lg * 8;    // + d16*16*SEQ + kv0 + kk*32

  for (int t = tb; t < te; ++t) {
    const int kv0 = t * 64;

    // K-frags direct from global (L1/L2): kf[kk][nt] = K[kv0+nt*16+lm][32kk+8lg..+7]
    short8 kf[2][4];
    #pragma unroll
    for (int kk = 0; kk < 2; ++kk)
      #pragma unroll
      for (int nt = 0; nt < 4; ++nt)
        kf[kk][nt] = *(const short8*)(kfp + (size_t)(kv0 + nt * 16) * NQKV + kk * 32);

    floatx4 s[4];
    #pragma unroll
    for (int nt = 0; nt < 4; ++nt) s[nt] = floatx4{0.f, 0.f, 0.f, 0.f};
    __builtin_amdgcn_s_setprio(1);
    #pragma unroll
    for (int kk = 0; kk < 2; ++kk)
      #pragma unroll
      for (int nt = 0; nt < 4; ++nt)
        s[nt] = mfma16(kf[kk][nt], qf[kk], s[nt]);
    __builtin_amdgcn_s_setprio(0);

    // mask (diagonal tile only) + in-lane max over this lane's 16 scores
    float pmax = -3e38f;
    if (t == x) {
      #pragma unroll
      for (int nt = 0; nt < 4; ++nt)
        #pragma unroll
        for (int r = 0; r < 4; ++r) {
          int kv = kv0 + nt * 16 + 4 * lg + r;
          float val = (kv > qrow_g) ? -3e38f : s[nt][r];
          s[nt][r] = val; pmax = fmaxf(pmax, val);
        }
    } else {
      #pragma unroll
      for (int nt = 0; nt < 4; ++nt)
        #pragma unroll
        for (int r = 0; r < 4; ++r) pmax = fmaxf(pmax, s[nt][r]);
    }
    // cross-lg reduce (lanes lm, lm+16, lm+32, lm+48 share q-row)
    pmax = fmaxf(pmax, __shfl_xor(pmax, 16));
    pmax = fmaxf(pmax, __shfl_xor(pmax, 32));

    // defer-max (T13)
    bool skip = __all(pmax <= mrow + 11.54f);
    float mnew = skip ? mrow : fmaxf(mrow, pmax);
    float corr = exp2fast(mrow - mnew);
    mrow = mnew;

    float psum = 0.f;
    #pragma unroll
    for (int nt = 0; nt < 4; ++nt)
      #pragma unroll
      for (int r = 0; r < 4; ++r) {
        float e = exp2fast(s[nt][r] - mnew);
        s[nt][r] = e; psum += e;
      }
    psum += __shfl_xor(psum, 16);
    psum += __shfl_xor(psum, 32);
    lrow = lrow * corr + psum;
    if (!skip) {
      #pragma unroll
      for (int nt = 0; nt < 4; ++nt)
        #pragma unroll
        for (int r = 0; r < 4; ++r) o[nt][r] *= corr;
    }

    // P^T -> per-wave LDS strip (no barrier; same-wave ordering via lgkmcnt)
    #pragma unroll
    for (int nt = 0; nt < 4; ++nt) {
      short4v pv;
      #pragma unroll
      for (int r = 0; r < 4; ++r) pv[r] = f2bf(s[nt][r]);
      *(short4v*)((char*)psw + lm * 144 + (nt * 16 + 4 * lg) * 2) = pv;
    }

    // O^T += V^T P^T ; V-frags direct from global: vt[nt*16+lm][kv0+32kk+8lg..+7]
    #pragma unroll
    for (int kk = 0; kk < 2; ++kk) {
      short8 vf[4];
      #pragma unroll
      for (int nt = 0; nt < 4; ++nt)
        vf[nt] = *(const short8*)(vfp + (size_t)(nt * 16) * SEQ + kv0 + kk * 32);
      short8 pf = *(const short8*)((const char*)psw + lm * 144 + (kk * 32 + lg * 8) * 2);
      __builtin_amdgcn_s_setprio(1);
      #pragma unroll
      for (int nt = 0; nt < 4; ++nt)
        o[nt] = mfma16(vf[nt], pf, o[nt]);
      __builtin_amdgcn_s_setprio(0);
    }
  }

  if (nch == 1) {
    const float linv = 1.0f / lrow;
    #pragma unroll
    for (int nt = 0; nt < 4; ++nt) {
      short4v ov;
      #pragma unroll
      for (int r = 0; r < 4; ++r) ov[r] = f2bf(o[nt][r] * linv);
      *(short4v*)&att[((size_t)(b * SEQ + qrow_g)) * HID + h * HD + nt * 16 + 4 * lg] = ov;
    }
  } else {
    const int g = x >> 2;
    const int slot2 = bh * 140 + (2 * g * g + 2 * g - 4 + (x & 3) * (g + 1)) + c;
    short* po = pO + (size_t)slot2 * 4096;
    const int ql = wid * 16 + lm;
    #pragma unroll
    for (int nt = 0; nt < 4; ++nt) {
      short4v ov;
      #pragma unroll
      for (int r = 0; r < 4; ++r) ov[r] = f2bf(o[nt][r]);
      *(short4v*)&po[ql * 64 + nt * 16 + 4 * lg] = ov;
    }
    if (lane < 16) {
      pml[slot2 * 128 + ql] = mrow;
      pml[slot2 * 128 + 64 + ql] = lrow;
    }
  }
}

// ---------- combine partials: grid (28, 32) ----------
__global__ __launch_bounds__(256) void combine_kernel(
    const short* __restrict__ pO, const float* __restrict__ pml,
    short* __restrict__ att)
{
  const int x = 4 + blockIdx.x;
  const int bh = blockIdx.y, b = bh >> 4, h = bh & 15;
  const int g = x >> 2;
  const int nch = g + 1;                  // 2..8
  const int tid = threadIdx.x;
  const int row = tid >> 2, d0 = (tid & 3) * 16;
  const int base_slot = bh * 140 + (2 * g * g + 2 * g - 4 + (x & 3) * (g + 1));

  float mv[8], lv[8], M = -3e38f;
  for (int cc = 0; cc < nch; ++cc) {
    mv[cc] = pml[(base_slot + cc) * 128 + row];
    lv[cc] = pml[(base_slot + cc) * 128 + 64 + row];
    M = fmaxf(M, mv[cc]);
  }
  float L = 0.f, w[8];
  for (int cc = 0; cc < nch; ++cc) {
    w[cc] = exp2fast(mv[cc] - M);
    L += lv[cc] * w[cc];
  }
  const float inv = 1.0f / L;

  float acc[16];
  #pragma unroll
  for (int j = 0; j < 16; ++j) acc[j] = 0.f;
  for (int cc = 0; cc < nch; ++cc) {
    const short* po = pO + (size_t)(base_slot + cc) * 4096 + row * 64 + d0;
    short8 v0 = *(const short8*)po, v1 = *(const short8*)(po + 8);
    #pragma unroll
    for (int j = 0; j < 8; ++j) {
      acc[j]     += bf2f(v0[j]) * w[cc];
      acc[j + 8] += bf2f(v1[j]) * w[cc];
    }
  }
  short8 o0, o1;
  #pragma unroll
  for (int j = 0; j < 8; ++j) {
    o0[j] = f2bf(acc[j] * inv);
    o1[j] = f2bf(acc[j + 8] * inv);
  }
  short* dst = att + ((size_t)(b * SEQ + x * 64 + row)) * HID + h * HD + d0;
  *(short8*)dst = o0;
  *(short8*)(dst + 8) = o1;
}

extern "C" void kernel_launch(void* const* d_in, const int* in_sizes, int n_in,
                              void* d_out, int out_size, void* d_ws, size_t ws_size,
                              hipStream_t stream) {
  (void)in_sizes; (void)n_in; (void)out_size; (void)ws_size;
  const float* x    = (const float*)d_in[0];
  const float* Wq   = (const float*)d_in[1];
  const float* bq   = (const float*)d_in[2];
  const float* Wk   = (const float*)d_in[3];
  const float* bk   = (const float*)d_in[4];
  const float* Wv   = (const float*)d_in[5];
  const float* bv   = (const float*)d_in[6];
  const float* Wmix = (const float*)d_in[7];
  const float* bmix = (const float*)d_in[8];
  float* out = (float*)d_out;

  char* w = (char*)d_ws;
  short* xb      = (short*)w; w += (size_t)8 << 20;
  short* Wt      = (short*)w; w += (size_t)6 << 20;
  short* Wmixt   = (short*)w; w += (size_t)2 << 20;
  float* biascat = (float*)w; w += (size_t)64 << 10;
  short* qkvb    = (short*)w; w += (size_t)24 << 20;
  short* vtb     = (short*)w; w += (size_t)8 << 20;
  short* ab      = (short*)w; w += (size_t)8 << 20;
  short* pO      = (short*)w; w += (size_t)140 * 32 * 4096 * 2;
  float* pml     = (float*)w;

  hipLaunchKernelGGL(convx_kernel, dim3(2048), dim3(256), 0, stream, x, xb);
  hipLaunchKernelGGL(transw_kernel, dim3(16, 16, 4), dim3(256), 0, stream,
                     Wq, Wk, Wv, Wmix, Wt, Wmixt);
  hipMemcpyAsync(biascat,        bq, 1024 * sizeof(float), hipMemcpyDeviceToDevice, stream);
  hipMemcpyAsync(biascat + 1024, bk, 1024 * sizeof(float), hipMemcpyDeviceToDevice, stream);
  hipMemcpyAsync(biascat + 2048, bv, 1024 * sizeof(float), hipMemcpyDeviceToDevice, stream);

  hipLaunchKernelGGL((gemm_kernel<128, 128, false, true>), dim3(NQKV / 128, M_ROWS / 128),
                     dim3(256), 0, stream, xb, Wt, biascat, (void*)qkvb, vtb, NQKV, DIN);

  hipLaunchKernelGGL(attn_kernel, dim3(4608), dim3(256), 0, stream,
                     qkvb, vtb, ab, pO, pml);
  hipLaunchKernelGGL(combine_kernel, dim3(28, BS * NH), dim3(256), 0, stream,
                     pO, pml, ab);

  hipLaunchKernelGGL((gemm_kernel<64, 128, true, false>), dim3(HID / 128, M_ROWS / 64),
                     dim3(256), 0, stream, ab, Wmixt, bmix, (void*)out, (short*)nullptr,
                     HID, DIN);
}

// Round 7
// 129.324 us; speedup vs baseline: 1.7245x; 1.7245x over previous
//
#include <hip/hip_runtime.h>
#include <hip/hip_bf16.h>

#define BS 2
#define SEQ 2048
#define DIN 1024
#define HID 1024
#define NH 16
#define HD 64
#define M_ROWS (BS*SEQ)
#define NQKV 3072

typedef __attribute__((ext_vector_type(8))) short short8;
typedef __attribute__((ext_vector_type(4))) short short4v;
typedef __attribute__((ext_vector_type(8))) __bf16 bf16x8;
typedef __attribute__((ext_vector_type(4))) float floatx4;

// native cast -> v_cvt_pk_bf16_f32 when paired (RNE)
__device__ __forceinline__ short f2bf(float f) {
  return __builtin_bit_cast(short, (__bf16)f);
}
__device__ __forceinline__ float bf2f(short s) {
  return __uint_as_float(((unsigned)(unsigned short)s) << 16);
}

__device__ __forceinline__ floatx4 mfma16(short8 a, short8 b, floatx4 c) {
  return __builtin_amdgcn_mfma_f32_16x16x32_bf16(
      __builtin_bit_cast(bf16x8, a), __builtin_bit_cast(bf16x8, b), c, 0, 0, 0);
}

__device__ __forceinline__ float exp2fast(float x) {
#if __has_builtin(__builtin_amdgcn_exp2f)
  return __builtin_amdgcn_exp2f(x);
#else
  return exp2f(x);
#endif
}

__device__ __forceinline__ void gload_lds16(const void* g, void* l) {
  __builtin_amdgcn_global_load_lds(
      (const __attribute__((address_space(1))) unsigned int*)g,
      (__attribute__((address_space(3))) unsigned int*)l, 16, 0, 0);
}

// Linear LDS helpers, row stride 72 shorts (144B = 4-bank shift/row; 2-way max)
__device__ __forceinline__ void lds_w8(short* base, int row, int colsh, short8 v) {
  *(short8*)((char*)base + row * 144 + colsh * 2) = v;
}
__device__ __forceinline__ void lds_w4(short* base, int row, int colsh, short4v v) {
  *(short4v*)((char*)base + row * 144 + colsh * 2) = v;
}
__device__ __forceinline__ short8 lds_r8(const short* base, int row, int colsh) {
  return *(const short8*)((const char*)base + row * 144 + colsh * 2);
}

// ---------- pre-pass: x fp32 -> bf16 ----------
__global__ __launch_bounds__(256) void convx_kernel(const float* __restrict__ x,
                                                    short* __restrict__ xb) {
  int gid = blockIdx.x * 256 + threadIdx.x;
  const float4* x4 = (const float4*)x;
  float4 v0 = x4[2 * gid], v1 = x4[2 * gid + 1];
  short8 o;
  o[0] = f2bf(v0.x); o[1] = f2bf(v0.y); o[2] = f2bf(v0.z); o[3] = f2bf(v0.w);
  o[4] = f2bf(v1.x); o[5] = f2bf(v1.y); o[6] = f2bf(v1.z); o[7] = f2bf(v1.w);
  *(short8*)&xb[(size_t)gid * 8] = o;
}

// ---------- pre-pass: W [K][N] fp32 -> Wt [N][K] bf16 ----------
__global__ __launch_bounds__(256) void transw_kernel(
    const float* __restrict__ Wq, const float* __restrict__ Wk,
    const float* __restrict__ Wv, const float* __restrict__ Wmix,
    short* __restrict__ Wt, short* __restrict__ Wmixt)
{
  __shared__ float Ws[64][65];
  const float* src; short* dst;
  switch (blockIdx.z) {
    case 0:  src = Wq;   dst = Wt;                 break;
    case 1:  src = Wk;   dst = Wt + (1u << 20);    break;
    case 2:  src = Wv;   dst = Wt + (2u << 20);    break;
    default: src = Wmix; dst = Wmixt;              break;
  }
  const int n0 = blockIdx.x * 64, k0 = blockIdx.y * 64;
  const int c = threadIdx.x & 63, r0 = threadIdx.x >> 6;
  #pragma unroll
  for (int i = 0; i < 16; ++i) {
    int rr = r0 + 4 * i;
    Ws[rr][c] = src[(size_t)(k0 + rr) * DIN + n0 + c];
  }
  __syncthreads();
  #pragma unroll
  for (int i = 0; i < 16; ++i) {
    int cc = r0 + 4 * i;
    dst[(size_t)(n0 + cc) * DIN + k0 + c] = f2bf(Ws[c][cc]);
  }
}

// ---------- GEMM: C[M][N] = A[M][K]bf16 @ Bt[N][K]bf16^T + bias ----------
template<int BM, int BN, bool OUT_F32, bool QKV>
__global__ __launch_bounds__(256) void gemm_kernel(
    const short* __restrict__ A, const short* __restrict__ Bt,
    const float* __restrict__ bias, void* __restrict__ Cp,
    short* __restrict__ vt, int Ndim, int Kdim)
{
  constexpr int MT = BM / 32, NT = BN / 32;
  __shared__ short As[BM * 32];
  __shared__ short Bs[BN * 32];
  const int tid = threadIdx.x;
  const int wid = tid >> 6, lane = tid & 63, lg = lane >> 4, lm = lane & 15;
  const int wr = wid >> 1, wc = wid & 1;
  const int m0 = blockIdx.y * BM, n0 = blockIdx.x * BN;

  floatx4 acc[MT][NT];
  #pragma unroll
  for (int i = 0; i < MT; ++i)
    #pragma unroll
    for (int j = 0; j < NT; ++j) acc[i][j] = floatx4{0.f, 0.f, 0.f, 0.f};

  for (int k0 = 0; k0 < Kdim; k0 += 32) {
    __syncthreads();
    #pragma unroll
    for (int j = 0; j < BM / 64; ++j) {
      int flat = tid + 256 * j;
      int row = flat >> 2, ch = (flat & 3) ^ ((row >> 1) & 3);
      gload_lds16(A + (size_t)(m0 + row) * Kdim + k0 + ch * 8,
                  (char*)As + wid * 1024 + j * 4096);
    }
    #pragma unroll
    for (int j = 0; j < BN / 64; ++j) {
      int flat = tid + 256 * j;
      int row = flat >> 2, ch = (flat & 3) ^ ((row >> 1) & 3);
      gload_lds16(Bt + (size_t)(n0 + row) * Kdim + k0 + ch * 8,
                  (char*)Bs + wid * 1024 + j * 4096);
    }
    __syncthreads();

    short8 a[MT], b[NT];
    #pragma unroll
    for (int mt = 0; mt < MT; ++mt) {
      int row = wr * (BM / 2) + mt * 16 + lm;
      a[mt] = *(const short8*)&As[row * 32 + (lg ^ ((row >> 1) & 3)) * 8];
    }
    #pragma unroll
    for (int nt = 0; nt < NT; ++nt) {
      int row = wc * (BN / 2) + nt * 16 + lm;
      b[nt] = *(const short8*)&Bs[row * 32 + (lg ^ ((row >> 1) & 3)) * 8];
    }
    #pragma unroll
    for (int mt = 0; mt < MT; ++mt)
      #pragma unroll
      for (int nt = 0; nt < NT; ++nt)
        acc[mt][nt] = mfma16(a[mt], b[nt], acc[mt][nt]);
  }

  #pragma unroll
  for (int mt = 0; mt < MT; ++mt) {
    const int row0 = m0 + wr * (BM / 2) + mt * 16 + 4 * lg;
    #pragma unroll
    for (int nt = 0; nt < NT; ++nt) {
      const int col = n0 + wc * (BN / 2) + nt * 16 + lm;
      const float bv = bias[col];
      if (QKV && n0 >= 2048) {
        int hd = col - 2048;
        int bb = row0 >> 11, s = row0 & 2047;
        short4v pv;
        #pragma unroll
        for (int r = 0; r < 4; ++r) pv[r] = f2bf(acc[mt][nt][r] + bv);
        *(short4v*)&vt[((size_t)(bb * (NH * HD) + hd)) * SEQ + s] = pv;
      } else {
        #pragma unroll
        for (int r = 0; r < 4; ++r) {
          float v = acc[mt][nt][r] + bv;
          if (OUT_F32) ((float*)Cp)[(size_t)(row0 + r) * Ndim + col] = v;
          else         ((short*)Cp)[(size_t)(row0 + r) * Ndim + col] = f2bf(v);
        }
      }
    }
  }
}

// ---------- split-KV flash attention, swapped-QK^T, fixed-max softmax ----------
// Block = (id, bh), id in [0,144): (q-tile x of 64 rows, chunk c of 4 kv-tiles).
// Softmax uses a FIXED shift MFIX (shift-invariance); no max tracking.
#define MFIX 12.0f
__global__ __launch_bounds__(256) void attn_kernel(
    const short* __restrict__ qkv, const short* __restrict__ vt,
    short* __restrict__ att, short* __restrict__ pO, float* __restrict__ pml)
{
  __shared__ short Ks[64 * 72];    // [kv][d]
  __shared__ short Vs[64 * 72];    // [d][kv]
  __shared__ short Ps[4 * 16 * 72];// per-wave P^T strip [q][kv]
  const int tid = threadIdx.x;
  const int wid = tid >> 6, lane = tid & 63, lg = lane >> 4, lm = lane & 15;

  int id = blockIdx.x, x, c;
  if (id < 4)        { x = id;                       c = 0;        }
  else if (id < 12)  { int t = id - 4;   x = 4  + (t >> 1); c = t & 1; }
  else if (id < 24)  { int t = id - 12;  x = 8  + t / 3;    c = t % 3; }
  else if (id < 40)  { int t = id - 24;  x = 12 + (t >> 2); c = t & 3; }
  else if (id < 60)  { int t = id - 40;  x = 16 + t / 5;    c = t % 5; }
  else if (id < 84)  { int t = id - 60;  x = 20 + t / 6;    c = t % 6; }
  else if (id < 112) { int t = id - 84;  x = 24 + t / 7;    c = t % 7; }
  else               { int t = id - 112; x = 28 + (t >> 3); c = t & 7; }
  const int nch = (x >> 2) + 1;
  const int tb = c * 4;
  const int te = min(tb + 4, x + 1);
  const int q0 = x * 64;
  const int bh = blockIdx.y, b = bh >> 4, h = bh & 15;
  const short* qp = qkv + (size_t)(b * SEQ) * NQKV + h * HD;
  const short* kp = qp + HID;
  const short* vp = vt + (size_t)bh * HD * SEQ;

  // Q fragments (B-operand), pre-scaled by log2(e)/sqrt(D); q-row = q0+wid*16+lm
  const float cl2 = 0.18033688011112042f;
  const int qrow_g = q0 + wid * 16 + lm;
  short8 qf[2];
  {
    const short* qrow = qp + (size_t)qrow_g * NQKV;
    #pragma unroll
    for (int kk = 0; kk < 2; ++kk) {
      short8 raw = *(const short8*)(qrow + kk * 32 + lg * 8);
      #pragma unroll
      for (int j = 0; j < 8; ++j) qf[kk][j] = f2bf(bf2f(raw[j]) * cl2);
    }
  }

  const int rstage = tid >> 3, c8 = (tid & 7) * 8;
  short8 kreg[2], vreg[2];
  #pragma unroll
  for (int i = 0; i < 2; ++i) {
    kreg[i] = *(const short8*)(kp + (size_t)(tb * 64 + rstage + 32 * i) * NQKV + c8);
    vreg[i] = *(const short8*)(vp + (size_t)(rstage + 32 * i) * SEQ + tb * 64 + c8);
  }

  short* psw = Ps + wid * 16 * 72;
  float lrow = 0.f;
  floatx4 o[4];   // O^T: o[nt][r] = O[d = nt*16+4lg+r][q = lm]
  #pragma unroll
  for (int nt = 0; nt < 4; ++nt) o[nt] = floatx4{0.f, 0.f, 0.f, 0.f};

  for (int t = tb; t < te; ++t) {
    __syncthreads();
    #pragma unroll
    for (int i = 0; i < 2; ++i) {
      lds_w8(Ks, rstage + 32 * i, c8, kreg[i]);
      lds_w8(Vs, rstage + 32 * i, c8, vreg[i]);
    }
    __syncthreads();
    if (t + 1 < te) {
      const int kv1 = (t + 1) * 64;
      #pragma unroll
      for (int i = 0; i < 2; ++i) {
        kreg[i] = *(const short8*)(kp + (size_t)(kv1 + rstage + 32 * i) * NQKV + c8);
        vreg[i] = *(const short8*)(vp + (size_t)(rstage + 32 * i) * SEQ + kv1 + c8);
      }
    }

    // S^T = K Q^T : s[nt] rows = kv (nt*16+4lg+r), col = q (lm)
    floatx4 s[4];
    #pragma unroll
    for (int nt = 0; nt < 4; ++nt) s[nt] = floatx4{0.f, 0.f, 0.f, 0.f};
    __builtin_amdgcn_s_setprio(1);
    #pragma unroll
    for (int kk = 0; kk < 2; ++kk)
      #pragma unroll
      for (int nt = 0; nt < 4; ++nt)
        s[nt] = mfma16(lds_r8(Ks, nt * 16 + lm, kk * 32 + lg * 8), qf[kk], s[nt]);
    __builtin_amdgcn_s_setprio(0);

    // causal mask on diagonal tile only
    if (t == x) {
      #pragma unroll
      for (int nt = 0; nt < 4; ++nt)
        #pragma unroll
        for (int r = 0; r < 4; ++r) {
          int kv = t * 64 + nt * 16 + 4 * lg + r;
          if (kv > qrow_g) s[nt][r] = -3e38f;
        }
    }

    // fixed-shift softmax: P = exp2(s - MFIX); l += sum(P)
    float psum = 0.f;
    #pragma unroll
    for (int nt = 0; nt < 4; ++nt)
      #pragma unroll
      for (int r = 0; r < 4; ++r) {
        float e = exp2fast(s[nt][r] - MFIX);
        s[nt][r] = e; psum += e;
      }
    psum += __shfl_xor(psum, 16);
    psum += __shfl_xor(psum, 32);
    lrow += psum;

    // P^T -> per-wave LDS strip [q=lm][kv], vectorized b64 writes
    #pragma unroll
    for (int nt = 0; nt < 4; ++nt) {
      short4v pv;
      #pragma unroll
      for (int r = 0; r < 4; ++r) pv[r] = f2bf(s[nt][r]);
      lds_w4(psw, lm, nt * 16 + 4 * lg, pv);
    }

    // O^T += V^T P^T : A = V^T frag (contiguous), B = P^T frag (contiguous)
    #pragma unroll
    for (int kk = 0; kk < 2; ++kk) {
      short8 pf = lds_r8(psw, lm, kk * 32 + lg * 8);
      __builtin_amdgcn_s_setprio(1);
      #pragma unroll
      for (int nt = 0; nt < 4; ++nt)
        o[nt] = mfma16(lds_r8(Vs, nt * 16 + lm, kk * 32 + lg * 8), pf, o[nt]);
      __builtin_amdgcn_s_setprio(0);
    }
  }

  if (nch == 1) {
    const float linv = 1.0f / lrow;
    #pragma unroll
    for (int nt = 0; nt < 4; ++nt) {
      short4v ov;
      #pragma unroll
      for (int r = 0; r < 4; ++r) ov[r] = f2bf(o[nt][r] * linv);
      *(short4v*)&att[((size_t)(b * SEQ + qrow_g)) * HID + h * HD + nt * 16 + 4 * lg] = ov;
    }
  } else {
    const int g = x >> 2;
    const int slot = bh * 140 + (2 * g * g + 2 * g - 4 + (x & 3) * (g + 1)) + c;
    short* po = pO + (size_t)slot * 4096;
    const int ql = wid * 16 + lm;
    #pragma unroll
    for (int nt = 0; nt < 4; ++nt) {
      short4v ov;
      #pragma unroll
      for (int r = 0; r < 4; ++r) ov[r] = f2bf(o[nt][r]);
      *(short4v*)&po[ql * 64 + nt * 16 + 4 * lg] = ov;
    }
    if (lane < 16) {
      pml[slot * 128 + 64 + ql] = lrow;   // only l needed (fixed shift)
    }
  }
}

// ---------- combine partials (fixed shift -> plain sums): grid (28, 32) ----------
__global__ __launch_bounds__(256) void combine_kernel(
    const short* __restrict__ pO, const float* __restrict__ pml,
    short* __restrict__ att)
{
  const int x = 4 + blockIdx.x;
  const int bh = blockIdx.y, b = bh >> 4, h = bh & 15;
  const int g = x >> 2;
  const int nch = g + 1;                  // 2..8
  const int tid = threadIdx.x;
  const int row = tid >> 2, d0 = (tid & 3) * 16;
  const int base_slot = bh * 140 + (2 * g * g + 2 * g - 4 + (x & 3) * (g + 1));

  float L = 0.f;
  for (int cc = 0; cc < nch; ++cc)
    L += pml[(base_slot + cc) * 128 + 64 + row];
  const float inv = 1.0f / L;

  float acc[16];
  #pragma unroll
  for (int j = 0; j < 16; ++j) acc[j] = 0.f;
  for (int cc = 0; cc < nch; ++cc) {
    const short* po = pO + (size_t)(base_slot + cc) * 4096 + row * 64 + d0;
    short8 v0 = *(const short8*)po, v1 = *(const short8*)(po + 8);
    #pragma unroll
    for (int j = 0; j < 8; ++j) {
      acc[j]     += bf2f(v0[j]);
      acc[j + 8] += bf2f(v1[j]);
    }
  }
  short8 o0, o1;
  #pragma unroll
  for (int j = 0; j < 8; ++j) {
    o0[j] = f2bf(acc[j] * inv);
    o1[j] = f2bf(acc[j + 8] * inv);
  }
  short* dst = att + ((size_t)(b * SEQ + x * 64 + row)) * HID + h * HD + d0;
  *(short8*)dst = o0;
  *(short8*)(dst + 8) = o1;
}

extern "C" void kernel_launch(void* const* d_in, const int* in_sizes, int n_in,
                              void* d_out, int out_size, void* d_ws, size_t ws_size,
                              hipStream_t stream) {
  (void)in_sizes; (void)n_in; (void)out_size; (void)ws_size;
  const float* x    = (const float*)d_in[0];
  const float* Wq   = (const float*)d_in[1];
  const float* bq   = (const float*)d_in[2];
  const float* Wk   = (const float*)d_in[3];
  const float* bk   = (const float*)d_in[4];
  const float* Wv   = (const float*)d_in[5];
  const float* bv   = (const float*)d_in[6];
  const float* Wmix = (const float*)d_in[7];
  const float* bmix = (const float*)d_in[8];
  float* out = (float*)d_out;

  char* w = (char*)d_ws;
  short* xb      = (short*)w; w += (size_t)8 << 20;
  short* Wt      = (short*)w; w += (size_t)6 << 20;
  short* Wmixt   = (short*)w; w += (size_t)2 << 20;
  float* biascat = (float*)w; w += (size_t)64 << 10;
  short* qkvb    = (short*)w; w += (size_t)24 << 20;
  short* vtb     = (short*)w; w += (size_t)8 << 20;
  short* ab      = (short*)w; w += (size_t)8 << 20;
  short* pO      = (short*)w; w += (size_t)140 * 32 * 4096 * 2;
  float* pml     = (float*)w;

  hipLaunchKernelGGL(convx_kernel, dim3(2048), dim3(256), 0, stream, x, xb);
  hipLaunchKernelGGL(transw_kernel, dim3(16, 16, 4), dim3(256), 0, stream,
                     Wq, Wk, Wv, Wmix, Wt, Wmixt);
  hipMemcpyAsync(biascat,        bq, 1024 * sizeof(float), hipMemcpyDeviceToDevice, stream);
  hipMemcpyAsync(biascat + 1024, bk, 1024 * sizeof(float), hipMemcpyDeviceToDevice, stream);
  hipMemcpyAsync(biascat + 2048, bv, 1024 * sizeof(float), hipMemcpyDeviceToDevice, stream);

  hipLaunchKernelGGL((gemm_kernel<128, 128, false, true>), dim3(NQKV / 128, M_ROWS / 128),
                     dim3(256), 0, stream, xb, Wt, biascat, (void*)qkvb, vtb, NQKV, DIN);

  hipLaunchKernelGGL(attn_kernel, dim3(144, BS * NH), dim3(256), 0, stream,
                     qkvb, vtb, ab, pO, pml);
  hipLaunchKernelGGL(combine_kernel, dim3(28, BS * NH), dim3(256), 0, stream,
                     pO, pml, ab);

  hipLaunchKernelGGL((gemm_kernel<64, 128, true, false>), dim3(HID / 128, M_ROWS / 64),
                     dim3(256), 0, stream, ab, Wmixt, bmix, (void*)out, (short*)nullptr,
                     HID, DIN);
}

// Round 8
// 125.147 us; speedup vs baseline: 1.7820x; 1.0334x over previous
//
#include <hip/hip_runtime.h>
#include <hip/hip_bf16.h>

#define BS 2
#define SEQ 2048
#define DIN 1024
#define HID 1024
#define NH 16
#define HD 64
#define M_ROWS (BS*SEQ)
#define NQKV 3072

typedef __attribute__((ext_vector_type(8))) short short8;
typedef __attribute__((ext_vector_type(4))) short short4v;
typedef __attribute__((ext_vector_type(8))) __bf16 bf16x8;
typedef __attribute__((ext_vector_type(4))) float floatx4;

// native cast -> v_cvt_pk_bf16_f32 when paired (RNE)
__device__ __forceinline__ short f2bf(float f) {
  return __builtin_bit_cast(short, (__bf16)f);
}
__device__ __forceinline__ float bf2f(short s) {
  return __uint_as_float(((unsigned)(unsigned short)s) << 16);
}

__device__ __forceinline__ floatx4 mfma16(short8 a, short8 b, floatx4 c) {
  return __builtin_amdgcn_mfma_f32_16x16x32_bf16(
      __builtin_bit_cast(bf16x8, a), __builtin_bit_cast(bf16x8, b), c, 0, 0, 0);
}

__device__ __forceinline__ float exp2fast(float x) {
#if __has_builtin(__builtin_amdgcn_exp2f)
  return __builtin_amdgcn_exp2f(x);
#else
  return exp2f(x);
#endif
}

__device__ __forceinline__ void gload_lds16(const void* g, void* l) {
  __builtin_amdgcn_global_load_lds(
      (const __attribute__((address_space(1))) unsigned int*)g,
      (__attribute__((address_space(3))) unsigned int*)l, 16, 0, 0);
}

// m214-verified LDS layout: 128B rows (power-2) + byte ^= (row&7)<<4, BOTH sides.
__device__ __forceinline__ void lds_w8s(short* base, int row, int colsh, short8 v) {
  *(short8*)((char*)base + row * 128 + ((colsh * 2) ^ ((row & 7) << 4))) = v;
}
__device__ __forceinline__ void lds_w4s(short* base, int row, int colsh, short4v v) {
  *(short4v*)((char*)base + row * 128 + ((colsh * 2) ^ ((row & 7) << 4))) = v;
}
__device__ __forceinline__ short8 lds_r8s(const short* base, int row, int colsh) {
  return *(const short8*)((const char*)base + row * 128 + ((colsh * 2) ^ ((row & 7) << 4)));
}

// ---------- pre-pass: x fp32 -> bf16 ----------
__global__ __launch_bounds__(256) void convx_kernel(const float* __restrict__ x,
                                                    short* __restrict__ xb) {
  int gid = blockIdx.x * 256 + threadIdx.x;
  const float4* x4 = (const float4*)x;
  float4 v0 = x4[2 * gid], v1 = x4[2 * gid + 1];
  short8 o;
  o[0] = f2bf(v0.x); o[1] = f2bf(v0.y); o[2] = f2bf(v0.z); o[3] = f2bf(v0.w);
  o[4] = f2bf(v1.x); o[5] = f2bf(v1.y); o[6] = f2bf(v1.z); o[7] = f2bf(v1.w);
  *(short8*)&xb[(size_t)gid * 8] = o;
}

// ---------- pre-pass: W [K][N] fp32 -> Wt [N][K] bf16 ----------
__global__ __launch_bounds__(256) void transw_kernel(
    const float* __restrict__ Wq, const float* __restrict__ Wk,
    const float* __restrict__ Wv, const float* __restrict__ Wmix,
    short* __restrict__ Wt, short* __restrict__ Wmixt)
{
  __shared__ float Ws[64][65];
  const float* src; short* dst;
  switch (blockIdx.z) {
    case 0:  src = Wq;   dst = Wt;                 break;
    case 1:  src = Wk;   dst = Wt + (1u << 20);    break;
    case 2:  src = Wv;   dst = Wt + (2u << 20);    break;
    default: src = Wmix; dst = Wmixt;              break;
  }
  const int n0 = blockIdx.x * 64, k0 = blockIdx.y * 64;
  const int c = threadIdx.x & 63, r0 = threadIdx.x >> 6;
  #pragma unroll
  for (int i = 0; i < 16; ++i) {
    int rr = r0 + 4 * i;
    Ws[rr][c] = src[(size_t)(k0 + rr) * DIN + n0 + c];
  }
  __syncthreads();
  #pragma unroll
  for (int i = 0; i < 16; ++i) {
    int cc = r0 + 4 * i;
    dst[(size_t)(n0 + cc) * DIN + k0 + c] = f2bf(Ws[c][cc]);
  }
}

// ---------- GEMM: C[M][N] = A[M][K]bf16 @ Bt[N][K]bf16^T + bias ----------
template<int BM, int BN, bool OUT_F32, bool QKV>
__global__ __launch_bounds__(256) void gemm_kernel(
    const short* __restrict__ A, const short* __restrict__ Bt,
    const float* __restrict__ bias, void* __restrict__ Cp,
    short* __restrict__ vt, int Ndim, int Kdim)
{
  constexpr int MT = BM / 32, NT = BN / 32;
  __shared__ short As[BM * 32];
  __shared__ short Bs[BN * 32];
  const int tid = threadIdx.x;
  const int wid = tid >> 6, lane = tid & 63, lg = lane >> 4, lm = lane & 15;
  const int wr = wid >> 1, wc = wid & 1;
  const int m0 = blockIdx.y * BM, n0 = blockIdx.x * BN;

  floatx4 acc[MT][NT];
  #pragma unroll
  for (int i = 0; i < MT; ++i)
    #pragma unroll
    for (int j = 0; j < NT; ++j) acc[i][j] = floatx4{0.f, 0.f, 0.f, 0.f};

  for (int k0 = 0; k0 < Kdim; k0 += 32) {
    __syncthreads();
    #pragma unroll
    for (int j = 0; j < BM / 64; ++j) {
      int flat = tid + 256 * j;
      int row = flat >> 2, ch = (flat & 3) ^ ((row >> 1) & 3);
      gload_lds16(A + (size_t)(m0 + row) * Kdim + k0 + ch * 8,
                  (char*)As + wid * 1024 + j * 4096);
    }
    #pragma unroll
    for (int j = 0; j < BN / 64; ++j) {
      int flat = tid + 256 * j;
      int row = flat >> 2, ch = (flat & 3) ^ ((row >> 1) & 3);
      gload_lds16(Bt + (size_t)(n0 + row) * Kdim + k0 + ch * 8,
                  (char*)Bs + wid * 1024 + j * 4096);
    }
    __syncthreads();

    short8 a[MT], b[NT];
    #pragma unroll
    for (int mt = 0; mt < MT; ++mt) {
      int row = wr * (BM / 2) + mt * 16 + lm;
      a[mt] = *(const short8*)&As[row * 32 + (lg ^ ((row >> 1) & 3)) * 8];
    }
    #pragma unroll
    for (int nt = 0; nt < NT; ++nt) {
      int row = wc * (BN / 2) + nt * 16 + lm;
      b[nt] = *(const short8*)&Bs[row * 32 + (lg ^ ((row >> 1) & 3)) * 8];
    }
    #pragma unroll
    for (int mt = 0; mt < MT; ++mt)
      #pragma unroll
      for (int nt = 0; nt < NT; ++nt)
        acc[mt][nt] = mfma16(a[mt], b[nt], acc[mt][nt]);
  }

  #pragma unroll
  for (int mt = 0; mt < MT; ++mt) {
    const int row0 = m0 + wr * (BM / 2) + mt * 16 + 4 * lg;
    #pragma unroll
    for (int nt = 0; nt < NT; ++nt) {
      const int col = n0 + wc * (BN / 2) + nt * 16 + lm;
      const float bv = bias[col];
      if (QKV && n0 >= 2048) {
        int hd = col - 2048;
        int bb = row0 >> 11, s = row0 & 2047;
        short4v pv;
        #pragma unroll
        for (int r = 0; r < 4; ++r) pv[r] = f2bf(acc[mt][nt][r] + bv);
        *(short4v*)&vt[((size_t)(bb * (NH * HD) + hd)) * SEQ + s] = pv;
      } else {
        #pragma unroll
        for (int r = 0; r < 4; ++r) {
          float v = acc[mt][nt][r] + bv;
          if (OUT_F32) ((float*)Cp)[(size_t)(row0 + r) * Ndim + col] = v;
          else         ((short*)Cp)[(size_t)(row0 + r) * Ndim + col] = f2bf(v);
        }
      }
    }
  }
}

// ---------- split-KV flash attention, swapped-QK^T, fixed-shift softmax ----------
// MFIX folded into MFMA acc init; denominator l computed via ones-row MFMA.
#define MFIX 12.0f
__global__ __launch_bounds__(256) void attn_kernel(
    const short* __restrict__ qkv, const short* __restrict__ vt,
    short* __restrict__ att, short* __restrict__ pO, float* __restrict__ pml)
{
  __shared__ short Ks[64 * 64];    // [kv][d], 128B rows, XOR-swizzled
  __shared__ short Vs[64 * 64];    // [d][kv], XOR-swizzled
  __shared__ short Ps[4 * 16 * 64];// per-wave P^T strip [q][kv], XOR-swizzled
  const int tid = threadIdx.x;
  const int wid = tid >> 6, lane = tid & 63, lg = lane >> 4, lm = lane & 15;

  int id = blockIdx.x, x, c;
  if (id < 4)        { x = id;                       c = 0;        }
  else if (id < 12)  { int t = id - 4;   x = 4  + (t >> 1); c = t & 1; }
  else if (id < 24)  { int t = id - 12;  x = 8  + t / 3;    c = t % 3; }
  else if (id < 40)  { int t = id - 24;  x = 12 + (t >> 2); c = t & 3; }
  else if (id < 60)  { int t = id - 40;  x = 16 + t / 5;    c = t % 5; }
  else if (id < 84)  { int t = id - 60;  x = 20 + t / 6;    c = t % 6; }
  else if (id < 112) { int t = id - 84;  x = 24 + t / 7;    c = t % 7; }
  else               { int t = id - 112; x = 28 + (t >> 3); c = t & 7; }
  const int nch = (x >> 2) + 1;
  const int tb = c * 4;
  const int te = min(tb + 4, x + 1);
  const int q0 = x * 64;
  const int bh = blockIdx.y, b = bh >> 4, h = bh & 15;
  const short* qp = qkv + (size_t)(b * SEQ) * NQKV + h * HD;
  const short* kp = qp + HID;
  const short* vp = vt + (size_t)bh * HD * SEQ;

  // Q fragments (B-operand), pre-scaled by log2(e)/sqrt(D); q-row = q0+wid*16+lm
  const float cl2 = 0.18033688011112042f;
  const int qrow_g = q0 + wid * 16 + lm;
  short8 qf[2];
  {
    const short* qrow = qp + (size_t)qrow_g * NQKV;
    #pragma unroll
    for (int kk = 0; kk < 2; ++kk) {
      short8 raw = *(const short8*)(qrow + kk * 32 + lg * 8);
      #pragma unroll
      for (int j = 0; j < 8; ++j) qf[kk][j] = f2bf(bf2f(raw[j]) * cl2);
    }
  }

  // all-ones A-fragment for the denominator MFMA
  short8 ones;
  #pragma unroll
  for (int j = 0; j < 8; ++j) ones[j] = (short)0x3F80;

  const int rstage = tid >> 3, c8 = (tid & 7) * 8;
  short8 kreg[2], vreg[2];
  #pragma unroll
  for (int i = 0; i < 2; ++i) {
    kreg[i] = *(const short8*)(kp + (size_t)(tb * 64 + rstage + 32 * i) * NQKV + c8);
    vreg[i] = *(const short8*)(vp + (size_t)(rstage + 32 * i) * SEQ + tb * 64 + c8);
  }

  short* psw = Ps + wid * 16 * 64;
  floatx4 o[4];   // O^T: o[nt][r] = O[d = nt*16+4lg+r][q = lm]
  floatx4 ol = floatx4{0.f, 0.f, 0.f, 0.f};   // denominator: ol[*] = l[q=lm]
  #pragma unroll
  for (int nt = 0; nt < 4; ++nt) o[nt] = floatx4{0.f, 0.f, 0.f, 0.f};

  for (int t = tb; t < te; ++t) {
    __syncthreads();
    #pragma unroll
    for (int i = 0; i < 2; ++i) {
      lds_w8s(Ks, rstage + 32 * i, c8, kreg[i]);
      lds_w8s(Vs, rstage + 32 * i, c8, vreg[i]);
    }
    __syncthreads();
    if (t + 1 < te) {
      const int kv1 = (t + 1) * 64;
      #pragma unroll
      for (int i = 0; i < 2; ++i) {
        kreg[i] = *(const short8*)(kp + (size_t)(kv1 + rstage + 32 * i) * NQKV + c8);
        vreg[i] = *(const short8*)(vp + (size_t)(rstage + 32 * i) * SEQ + kv1 + c8);
      }
    }

    // S^T = K Q^T - MFIX (shift folded into acc init)
    floatx4 s[4];
    #pragma unroll
    for (int nt = 0; nt < 4; ++nt) s[nt] = floatx4{-MFIX, -MFIX, -MFIX, -MFIX};
    __builtin_amdgcn_s_setprio(1);
    #pragma unroll
    for (int kk = 0; kk < 2; ++kk)
      #pragma unroll
      for (int nt = 0; nt < 4; ++nt)
        s[nt] = mfma16(lds_r8s(Ks, nt * 16 + lm, kk * 32 + lg * 8), qf[kk], s[nt]);
    __builtin_amdgcn_s_setprio(0);

    // causal mask on diagonal tile only
    if (t == x) {
      #pragma unroll
      for (int nt = 0; nt < 4; ++nt)
        #pragma unroll
        for (int r = 0; r < 4; ++r) {
          int kv = t * 64 + nt * 16 + 4 * lg + r;
          if (kv > qrow_g) s[nt][r] = -3e38f;
        }
    }

    // P = exp2(S^T) -> per-wave LDS strip (zero cross-lane ops)
    #pragma unroll
    for (int nt = 0; nt < 4; ++nt) {
      short4v pv;
      #pragma unroll
      for (int r = 0; r < 4; ++r) pv[r] = f2bf(exp2fast(s[nt][r]));
      lds_w4s(psw, lm, nt * 16 + 4 * lg, pv);
    }

    // O^T += V^T P^T ; l += 1^T P^T (denominator on the matrix pipe)
    #pragma unroll
    for (int kk = 0; kk < 2; ++kk) {
      short8 pf = lds_r8s(psw, lm, kk * 32 + lg * 8);
      __builtin_amdgcn_s_setprio(1);
      #pragma unroll
      for (int nt = 0; nt < 4; ++nt)
        o[nt] = mfma16(lds_r8s(Vs, nt * 16 + lm, kk * 32 + lg * 8), pf, o[nt]);
      ol = mfma16(ones, pf, ol);
      __builtin_amdgcn_s_setprio(0);
    }
  }

  if (nch == 1) {
    const float linv = 1.0f / ol[0];
    #pragma unroll
    for (int nt = 0; nt < 4; ++nt) {
      short4v ov;
      #pragma unroll
      for (int r = 0; r < 4; ++r) ov[r] = f2bf(o[nt][r] * linv);
      *(short4v*)&att[((size_t)(b * SEQ + qrow_g)) * HID + h * HD + nt * 16 + 4 * lg] = ov;
    }
  } else {
    const int g = x >> 2;
    const int slot = bh * 140 + (2 * g * g + 2 * g - 4 + (x & 3) * (g + 1)) + c;
    short* po = pO + (size_t)slot * 4096;
    const int ql = wid * 16 + lm;
    #pragma unroll
    for (int nt = 0; nt < 4; ++nt) {
      short4v ov;
      #pragma unroll
      for (int r = 0; r < 4; ++r) ov[r] = f2bf(o[nt][r]);
      *(short4v*)&po[ql * 64 + nt * 16 + 4 * lg] = ov;
    }
    if (lane < 16) {
      pml[slot * 128 + 64 + ql] = ol[0];   // only l needed (fixed shift)
    }
  }
}

// ---------- combine partials (fixed shift -> plain sums): grid (28, 32) ----------
__global__ __launch_bounds__(256) void combine_kernel(
    const short* __restrict__ pO, const float* __restrict__ pml,
    short* __restrict__ att)
{
  const int x = 4 + blockIdx.x;
  const int bh = blockIdx.y, b = bh >> 4, h = bh & 15;
  const int g = x >> 2;
  const int nch = g + 1;                  // 2..8
  const int tid = threadIdx.x;
  const int row = tid >> 2, d0 = (tid & 3) * 16;
  const int base_slot = bh * 140 + (2 * g * g + 2 * g - 4 + (x & 3) * (g + 1));

  float L = 0.f;
  for (int cc = 0; cc < nch; ++cc)
    L += pml[(base_slot + cc) * 128 + 64 + row];
  const float inv = 1.0f / L;

  float acc[16];
  #pragma unroll
  for (int j = 0; j < 16; ++j) acc[j] = 0.f;
  for (int cc = 0; cc < nch; ++cc) {
    const short* po = pO + (size_t)(base_slot + cc) * 4096 + row * 64 + d0;
    short8 v0 = *(const short8*)po, v1 = *(const short8*)(po + 8);
    #pragma unroll
    for (int j = 0; j < 8; ++j) {
      acc[j]     += bf2f(v0[j]);
      acc[j + 8] += bf2f(v1[j]);
    }
  }
  short8 o0, o1;
  #pragma unroll
  for (int j = 0; j < 8; ++j) {
    o0[j] = f2bf(acc[j] * inv);
    o1[j] = f2bf(acc[j + 8] * inv);
  }
  short* dst = att + ((size_t)(b * SEQ + x * 64 + row)) * HID + h * HD + d0;
  *(short8*)dst = o0;
  *(short8*)(dst + 8) = o1;
}

extern "C" void kernel_launch(void* const* d_in, const int* in_sizes, int n_in,
                              void* d_out, int out_size, void* d_ws, size_t ws_size,
                              hipStream_t stream) {
  (void)in_sizes; (void)n_in; (void)out_size; (void)ws_size;
  const float* x    = (const float*)d_in[0];
  const float* Wq   = (const float*)d_in[1];
  const float* bq   = (const float*)d_in[2];
  const float* Wk   = (const float*)d_in[3];
  const float* bk   = (const float*)d_in[4];
  const float* Wv   = (const float*)d_in[5];
  const float* bv   = (const float*)d_in[6];
  const float* Wmix = (const float*)d_in[7];
  const float* bmix = (const float*)d_in[8];
  float* out = (float*)d_out;

  char* w = (char*)d_ws;
  short* xb      = (short*)w; w += (size_t)8 << 20;
  short* Wt      = (short*)w; w += (size_t)6 << 20;
  short* Wmixt   = (short*)w; w += (size_t)2 << 20;
  float* biascat = (float*)w; w += (size_t)64 << 10;
  short* qkvb    = (short*)w; w += (size_t)24 << 20;
  short* vtb     = (short*)w; w += (size_t)8 << 20;
  short* ab      = (short*)w; w += (size_t)8 << 20;
  short* pO      = (short*)w; w += (size_t)140 * 32 * 4096 * 2;
  float* pml     = (float*)w;

  hipLaunchKernelGGL(convx_kernel, dim3(2048), dim3(256), 0, stream, x, xb);
  hipLaunchKernelGGL(transw_kernel, dim3(16, 16, 4), dim3(256), 0, stream,
                     Wq, Wk, Wv, Wmix, Wt, Wmixt);
  hipMemcpyAsync(biascat,        bq, 1024 * sizeof(float), hipMemcpyDeviceToDevice, stream);
  hipMemcpyAsync(biascat + 1024, bk, 1024 * sizeof(float), hipMemcpyDeviceToDevice, stream);
  hipMemcpyAsync(biascat + 2048, bv, 1024 * sizeof(float), hipMemcpyDeviceToDevice, stream);

  hipLaunchKernelGGL((gemm_kernel<128, 128, false, true>), dim3(NQKV / 128, M_ROWS / 128),
                     dim3(256), 0, stream, xb, Wt, biascat, (void*)qkvb, vtb, NQKV, DIN);

  hipLaunchKernelGGL(attn_kernel, dim3(144, BS * NH), dim3(256), 0, stream,
                     qkvb, vtb, ab, pO, pml);
  hipLaunchKernelGGL(combine_kernel, dim3(28, BS * NH), dim3(256), 0, stream,
                     pO, pml, ab);

  hipLaunchKernelGGL((gemm_kernel<64, 128, true, false>), dim3(HID / 128, M_ROWS / 64),
                     dim3(256), 0, stream, ab, Wmixt, bmix, (void*)out, (short*)nullptr,
                     HID, DIN);
}

// Round 9
// 115.277 us; speedup vs baseline: 1.9346x; 1.0856x over previous
//
#include <hip/hip_runtime.h>
#include <hip/hip_bf16.h>

#define BS 2
#define SEQ 2048
#define DIN 1024
#define HID 1024
#define NH 16
#define HD 64
#define M_ROWS (BS*SEQ)
#define NQKV 3072

typedef __attribute__((ext_vector_type(8))) short short8;
typedef __attribute__((ext_vector_type(4))) short short4v;
typedef __attribute__((ext_vector_type(8))) __bf16 bf16x8;
typedef __attribute__((ext_vector_type(4))) float floatx4;

// native cast -> v_cvt_pk_bf16_f32 when paired (RNE)
__device__ __forceinline__ short f2bf(float f) {
  return __builtin_bit_cast(short, (__bf16)f);
}
__device__ __forceinline__ float bf2f(short s) {
  return __uint_as_float(((unsigned)(unsigned short)s) << 16);
}

__device__ __forceinline__ floatx4 mfma16(short8 a, short8 b, floatx4 c) {
  return __builtin_amdgcn_mfma_f32_16x16x32_bf16(
      __builtin_bit_cast(bf16x8, a), __builtin_bit_cast(bf16x8, b), c, 0, 0, 0);
}

__device__ __forceinline__ float exp2fast(float x) {
#if __has_builtin(__builtin_amdgcn_exp2f)
  return __builtin_amdgcn_exp2f(x);
#else
  return exp2f(x);
#endif
}

__device__ __forceinline__ void gload_lds16(const void* g, void* l) {
  __builtin_amdgcn_global_load_lds(
      (const __attribute__((address_space(1))) unsigned int*)g,
      (__attribute__((address_space(3))) unsigned int*)l, 16, 0, 0);
}

// m214-verified LDS layout: 128B rows (power-2) + byte ^= (row&7)<<4, BOTH sides.
__device__ __forceinline__ void lds_w8s(short* base, int row, int colsh, short8 v) {
  *(short8*)((char*)base + row * 128 + ((colsh * 2) ^ ((row & 7) << 4))) = v;
}
__device__ __forceinline__ void lds_w4s(short* base, int row, int colsh, short4v v) {
  *(short4v*)((char*)base + row * 128 + ((colsh * 2) ^ ((row & 7) << 4))) = v;
}
__device__ __forceinline__ short8 lds_r8s(const short* base, int row, int colsh) {
  return *(const short8*)((const char*)base + row * 128 + ((colsh * 2) ^ ((row & 7) << 4)));
}

// ---------- pre-pass: x fp32 -> bf16 ----------
__global__ __launch_bounds__(256) void convx_kernel(const float* __restrict__ x,
                                                    short* __restrict__ xb) {
  int gid = blockIdx.x * 256 + threadIdx.x;
  const float4* x4 = (const float4*)x;
  float4 v0 = x4[2 * gid], v1 = x4[2 * gid + 1];
  short8 o;
  o[0] = f2bf(v0.x); o[1] = f2bf(v0.y); o[2] = f2bf(v0.z); o[3] = f2bf(v0.w);
  o[4] = f2bf(v1.x); o[5] = f2bf(v1.y); o[6] = f2bf(v1.z); o[7] = f2bf(v1.w);
  *(short8*)&xb[(size_t)gid * 8] = o;
}

// ---------- pre-pass: W [K][N] fp32 -> Wt [N][K] bf16 ----------
__global__ __launch_bounds__(256) void transw_kernel(
    const float* __restrict__ Wq, const float* __restrict__ Wk,
    const float* __restrict__ Wv, const float* __restrict__ Wmix,
    short* __restrict__ Wt, short* __restrict__ Wmixt)
{
  __shared__ float Ws[64][65];
  const float* src; short* dst;
  switch (blockIdx.z) {
    case 0:  src = Wq;   dst = Wt;                 break;
    case 1:  src = Wk;   dst = Wt + (1u << 20);    break;
    case 2:  src = Wv;   dst = Wt + (2u << 20);    break;
    default: src = Wmix; dst = Wmixt;              break;
  }
  const int n0 = blockIdx.x * 64, k0 = blockIdx.y * 64;
  const int c = threadIdx.x & 63, r0 = threadIdx.x >> 6;
  #pragma unroll
  for (int i = 0; i < 16; ++i) {
    int rr = r0 + 4 * i;
    Ws[rr][c] = src[(size_t)(k0 + rr) * DIN + n0 + c];
  }
  __syncthreads();
  #pragma unroll
  for (int i = 0; i < 16; ++i) {
    int cc = r0 + 4 * i;
    dst[(size_t)(n0 + cc) * DIN + k0 + c] = f2bf(Ws[c][cc]);
  }
}

// ---------- GEMM (BK=64): C[M][N] = A[M][K]bf16 @ Bt[N][K]bf16^T + bias ----------
// 32 MFMA / 16 ds_read_b128 / 8 global_load_lds per K-step; half the barriers
// of the BK=32 version. Chunk-XOR involution: src ch=(flat&7)^(row&7),
// read ch=(kk*4+lg)^(row&7)  -> 2 lanes/slot per 16-lane group (free, m136).
template<int BM, int BN, bool OUT_F32, bool QKV>
__global__ __launch_bounds__(256) void gemm_kernel(
    const short* __restrict__ A, const short* __restrict__ Bt,
    const float* __restrict__ bias, void* __restrict__ Cp,
    short* __restrict__ vt, int Ndim, int Kdim)
{
  constexpr int MT = BM / 32, NT = BN / 32;
  __shared__ short As[BM * 64];
  __shared__ short Bs[BN * 64];
  const int tid = threadIdx.x;
  const int wid = tid >> 6, lane = tid & 63, lg = lane >> 4, lm = lane & 15;
  const int wr = wid >> 1, wc = wid & 1;
  const int m0 = blockIdx.y * BM, n0 = blockIdx.x * BN;

  floatx4 acc[MT][NT];
  #pragma unroll
  for (int i = 0; i < MT; ++i)
    #pragma unroll
    for (int j = 0; j < NT; ++j) acc[i][j] = floatx4{0.f, 0.f, 0.f, 0.f};

  for (int k0 = 0; k0 < Kdim; k0 += 64) {
    __syncthreads();
    #pragma unroll
    for (int j = 0; j < BM / 32; ++j) {
      int flat = tid + 256 * j;
      int row = flat >> 3, ch = (flat & 7) ^ (row & 7);
      gload_lds16(A + (size_t)(m0 + row) * Kdim + k0 + ch * 8,
                  (char*)As + wid * 1024 + j * 4096);
    }
    #pragma unroll
    for (int j = 0; j < BN / 32; ++j) {
      int flat = tid + 256 * j;
      int row = flat >> 3, ch = (flat & 7) ^ (row & 7);
      gload_lds16(Bt + (size_t)(n0 + row) * Kdim + k0 + ch * 8,
                  (char*)Bs + wid * 1024 + j * 4096);
    }
    __syncthreads();

    #pragma unroll
    for (int kk = 0; kk < 2; ++kk) {
      short8 a[MT], b[NT];
      #pragma unroll
      for (int mt = 0; mt < MT; ++mt) {
        int row = wr * (BM / 2) + mt * 16 + lm;
        int ch = (kk * 4 + lg) ^ (row & 7);
        a[mt] = *(const short8*)&As[row * 64 + ch * 8];
      }
      #pragma unroll
      for (int nt = 0; nt < NT; ++nt) {
        int row = wc * (BN / 2) + nt * 16 + lm;
        int ch = (kk * 4 + lg) ^ (row & 7);
        b[nt] = *(const short8*)&Bs[row * 64 + ch * 8];
      }
      #pragma unroll
      for (int mt = 0; mt < MT; ++mt)
        #pragma unroll
        for (int nt = 0; nt < NT; ++nt)
          acc[mt][nt] = mfma16(a[mt], b[nt], acc[mt][nt]);
    }
  }

  #pragma unroll
  for (int mt = 0; mt < MT; ++mt) {
    const int row0 = m0 + wr * (BM / 2) + mt * 16 + 4 * lg;
    #pragma unroll
    for (int nt = 0; nt < NT; ++nt) {
      const int col = n0 + wc * (BN / 2) + nt * 16 + lm;
      const float bv = bias[col];
      if (QKV && n0 >= 2048) {
        int hd = col - 2048;
        int bb = row0 >> 11, s = row0 & 2047;
        short4v pv;
        #pragma unroll
        for (int r = 0; r < 4; ++r) pv[r] = f2bf(acc[mt][nt][r] + bv);
        *(short4v*)&vt[((size_t)(bb * (NH * HD) + hd)) * SEQ + s] = pv;
      } else {
        #pragma unroll
        for (int r = 0; r < 4; ++r) {
          float v = acc[mt][nt][r] + bv;
          if (OUT_F32) ((float*)Cp)[(size_t)(row0 + r) * Ndim + col] = v;
          else         ((short*)Cp)[(size_t)(row0 + r) * Ndim + col] = f2bf(v);
        }
      }
    }
  }
}

// ---------- split-KV flash attention, swapped-QK^T, fixed-shift softmax ----------
// MFIX folded into MFMA acc init; denominator l computed via ones-row MFMA.
#define MFIX 12.0f
__global__ __launch_bounds__(256) void attn_kernel(
    const short* __restrict__ qkv, const short* __restrict__ vt,
    short* __restrict__ att, short* __restrict__ pO, float* __restrict__ pml)
{
  __shared__ short Ks[64 * 64];    // [kv][d], 128B rows, XOR-swizzled
  __shared__ short Vs[64 * 64];    // [d][kv], XOR-swizzled
  __shared__ short Ps[4 * 16 * 64];// per-wave P^T strip [q][kv], XOR-swizzled
  const int tid = threadIdx.x;
  const int wid = tid >> 6, lane = tid & 63, lg = lane >> 4, lm = lane & 15;

  int id = blockIdx.x, x, c;
  if (id < 4)        { x = id;                       c = 0;        }
  else if (id < 12)  { int t = id - 4;   x = 4  + (t >> 1); c = t & 1; }
  else if (id < 24)  { int t = id - 12;  x = 8  + t / 3;    c = t % 3; }
  else if (id < 40)  { int t = id - 24;  x = 12 + (t >> 2); c = t & 3; }
  else if (id < 60)  { int t = id - 40;  x = 16 + t / 5;    c = t % 5; }
  else if (id < 84)  { int t = id - 60;  x = 20 + t / 6;    c = t % 6; }
  else if (id < 112) { int t = id - 84;  x = 24 + t / 7;    c = t % 7; }
  else               { int t = id - 112; x = 28 + (t >> 3); c = t & 7; }
  const int nch = (x >> 2) + 1;
  const int tb = c * 4;
  const int te = min(tb + 4, x + 1);
  const int q0 = x * 64;
  const int bh = blockIdx.y, b = bh >> 4, h = bh & 15;
  const short* qp = qkv + (size_t)(b * SEQ) * NQKV + h * HD;
  const short* kp = qp + HID;
  const short* vp = vt + (size_t)bh * HD * SEQ;

  // Q fragments (B-operand), pre-scaled by log2(e)/sqrt(D); q-row = q0+wid*16+lm
  const float cl2 = 0.18033688011112042f;
  const int qrow_g = q0 + wid * 16 + lm;
  short8 qf[2];
  {
    const short* qrow = qp + (size_t)qrow_g * NQKV;
    #pragma unroll
    for (int kk = 0; kk < 2; ++kk) {
      short8 raw = *(const short8*)(qrow + kk * 32 + lg * 8);
      #pragma unroll
      for (int j = 0; j < 8; ++j) qf[kk][j] = f2bf(bf2f(raw[j]) * cl2);
    }
  }

  // all-ones A-fragment for the denominator MFMA
  short8 ones;
  #pragma unroll
  for (int j = 0; j < 8; ++j) ones[j] = (short)0x3F80;

  const int rstage = tid >> 3, c8 = (tid & 7) * 8;
  short8 kreg[2], vreg[2];
  #pragma unroll
  for (int i = 0; i < 2; ++i) {
    kreg[i] = *(const short8*)(kp + (size_t)(tb * 64 + rstage + 32 * i) * NQKV + c8);
    vreg[i] = *(const short8*)(vp + (size_t)(rstage + 32 * i) * SEQ + tb * 64 + c8);
  }

  short* psw = Ps + wid * 16 * 64;
  floatx4 o[4];   // O^T: o[nt][r] = O[d = nt*16+4lg+r][q = lm]
  floatx4 ol = floatx4{0.f, 0.f, 0.f, 0.f};   // denominator: ol[*] = l[q=lm]
  #pragma unroll
  for (int nt = 0; nt < 4; ++nt) o[nt] = floatx4{0.f, 0.f, 0.f, 0.f};

  for (int t = tb; t < te; ++t) {
    __syncthreads();
    #pragma unroll
    for (int i = 0; i < 2; ++i) {
      lds_w8s(Ks, rstage + 32 * i, c8, kreg[i]);
      lds_w8s(Vs, rstage + 32 * i, c8, vreg[i]);
    }
    __syncthreads();
    if (t + 1 < te) {
      const int kv1 = (t + 1) * 64;
      #pragma unroll
      for (int i = 0; i < 2; ++i) {
        kreg[i] = *(const short8*)(kp + (size_t)(kv1 + rstage + 32 * i) * NQKV + c8);
        vreg[i] = *(const short8*)(vp + (size_t)(rstage + 32 * i) * SEQ + kv1 + c8);
      }
    }

    // S^T = K Q^T - MFIX (shift folded into acc init)
    floatx4 s[4];
    #pragma unroll
    for (int nt = 0; nt < 4; ++nt) s[nt] = floatx4{-MFIX, -MFIX, -MFIX, -MFIX};
    __builtin_amdgcn_s_setprio(1);
    #pragma unroll
    for (int kk = 0; kk < 2; ++kk)
      #pragma unroll
      for (int nt = 0; nt < 4; ++nt)
        s[nt] = mfma16(lds_r8s(Ks, nt * 16 + lm, kk * 32 + lg * 8), qf[kk], s[nt]);
    __builtin_amdgcn_s_setprio(0);

    // causal mask on diagonal tile only
    if (t == x) {
      #pragma unroll
      for (int nt = 0; nt < 4; ++nt)
        #pragma unroll
        for (int r = 0; r < 4; ++r) {
          int kv = t * 64 + nt * 16 + 4 * lg + r;
          if (kv > qrow_g) s[nt][r] = -3e38f;
        }
    }

    // P = exp2(S^T) -> per-wave LDS strip (zero cross-lane ops)
    #pragma unroll
    for (int nt = 0; nt < 4; ++nt) {
      short4v pv;
      #pragma unroll
      for (int r = 0; r < 4; ++r) pv[r] = f2bf(exp2fast(s[nt][r]));
      lds_w4s(psw, lm, nt * 16 + 4 * lg, pv);
    }

    // O^T += V^T P^T ; l += 1^T P^T (denominator on the matrix pipe)
    #pragma unroll
    for (int kk = 0; kk < 2; ++kk) {
      short8 pf = lds_r8s(psw, lm, kk * 32 + lg * 8);
      __builtin_amdgcn_s_setprio(1);
      #pragma unroll
      for (int nt = 0; nt < 4; ++nt)
        o[nt] = mfma16(lds_r8s(Vs, nt * 16 + lm, kk * 32 + lg * 8), pf, o[nt]);
      ol = mfma16(ones, pf, ol);
      __builtin_amdgcn_s_setprio(0);
    }
  }

  if (nch == 1) {
    const float linv = 1.0f / ol[0];
    #pragma unroll
    for (int nt = 0; nt < 4; ++nt) {
      short4v ov;
      #pragma unroll
      for (int r = 0; r < 4; ++r) ov[r] = f2bf(o[nt][r] * linv);
      *(short4v*)&att[((size_t)(b * SEQ + qrow_g)) * HID + h * HD + nt * 16 + 4 * lg] = ov;
    }
  } else {
    const int g = x >> 2;
    const int slot = bh * 140 + (2 * g * g + 2 * g - 4 + (x & 3) * (g + 1)) + c;
    short* po = pO + (size_t)slot * 4096;
    const int ql = wid * 16 + lm;
    #pragma unroll
    for (int nt = 0; nt < 4; ++nt) {
      short4v ov;
      #pragma unroll
      for (int r = 0; r < 4; ++r) ov[r] = f2bf(o[nt][r]);
      *(short4v*)&po[ql * 64 + nt * 16 + 4 * lg] = ov;
    }
    if (lane < 16) {
      pml[slot * 128 + 64 + ql] = ol[0];   // only l needed (fixed shift)
    }
  }
}

// ---------- combine partials (fixed shift -> plain sums): grid (28, 32) ----------
__global__ __launch_bounds__(256) void combine_kernel(
    const short* __restrict__ pO, const float* __restrict__ pml,
    short* __restrict__ att)
{
  const int x = 4 + blockIdx.x;
  const int bh = blockIdx.y, b = bh >> 4, h = bh & 15;
  const int g = x >> 2;
  const int nch = g + 1;                  // 2..8
  const int tid = threadIdx.x;
  const int row = tid >> 2, d0 = (tid & 3) * 16;
  const int base_slot = bh * 140 + (2 * g * g + 2 * g - 4 + (x & 3) * (g + 1));

  float L = 0.f;
  for (int cc = 0; cc < nch; ++cc)
    L += pml[(base_slot + cc) * 128 + 64 + row];
  const float inv = 1.0f / L;

  float acc[16];
  #pragma unroll
  for (int j = 0; j < 16; ++j) acc[j] = 0.f;
  for (int cc = 0; cc < nch; ++cc) {
    const short* po = pO + (size_t)(base_slot + cc) * 4096 + row * 64 + d0;
    short8 v0 = *(const short8*)po, v1 = *(const short8*)(po + 8);
    #pragma unroll
    for (int j = 0; j < 8; ++j) {
      acc[j]     += bf2f(v0[j]);
      acc[j + 8] += bf2f(v1[j]);
    }
  }
  short8 o0, o1;
  #pragma unroll
  for (int j = 0; j < 8; ++j) {
    o0[j] = f2bf(acc[j] * inv);
    o1[j] = f2bf(acc[j + 8] * inv);
  }
  short* dst = att + ((size_t)(b * SEQ + x * 64 + row)) * HID + h * HD + d0;
  *(short8*)dst = o0;
  *(short8*)(dst + 8) = o1;
}

extern "C" void kernel_launch(void* const* d_in, const int* in_sizes, int n_in,
                              void* d_out, int out_size, void* d_ws, size_t ws_size,
                              hipStream_t stream) {
  (void)in_sizes; (void)n_in; (void)out_size; (void)ws_size;
  const float* x    = (const float*)d_in[0];
  const float* Wq   = (const float*)d_in[1];
  const float* bq   = (const float*)d_in[2];
  const float* Wk   = (const float*)d_in[3];
  const float* bk   = (const float*)d_in[4];
  const float* Wv   = (const float*)d_in[5];
  const float* bv   = (const float*)d_in[6];
  const float* Wmix = (const float*)d_in[7];
  const float* bmix = (const float*)d_in[8];
  float* out = (float*)d_out;

  char* w = (char*)d_ws;
  short* xb      = (short*)w; w += (size_t)8 << 20;
  short* Wt      = (short*)w; w += (size_t)6 << 20;
  short* Wmixt   = (short*)w; w += (size_t)2 << 20;
  float* biascat = (float*)w; w += (size_t)64 << 10;
  short* qkvb    = (short*)w; w += (size_t)24 << 20;
  short* vtb     = (short*)w; w += (size_t)8 << 20;
  short* ab      = (short*)w; w += (size_t)8 << 20;
  short* pO      = (short*)w; w += (size_t)140 * 32 * 4096 * 2;
  float* pml     = (float*)w;

  hipLaunchKernelGGL(convx_kernel, dim3(2048), dim3(256), 0, stream, x, xb);
  hipLaunchKernelGGL(transw_kernel, dim3(16, 16, 4), dim3(256), 0, stream,
                     Wq, Wk, Wv, Wmix, Wt, Wmixt);
  hipMemcpyAsync(biascat,        bq, 1024 * sizeof(float), hipMemcpyDeviceToDevice, stream);
  hipMemcpyAsync(biascat + 1024, bk, 1024 * sizeof(float), hipMemcpyDeviceToDevice, stream);
  hipMemcpyAsync(biascat + 2048, bv, 1024 * sizeof(float), hipMemcpyDeviceToDevice, stream);

  hipLaunchKernelGGL((gemm_kernel<128, 128, false, true>), dim3(NQKV / 128, M_ROWS / 128),
                     dim3(256), 0, stream, xb, Wt, biascat, (void*)qkvb, vtb, NQKV, DIN);

  hipLaunchKernelGGL(attn_kernel, dim3(144, BS * NH), dim3(256), 0, stream,
                     qkvb, vtb, ab, pO, pml);
  hipLaunchKernelGGL(combine_kernel, dim3(28, BS * NH), dim3(256), 0, stream,
                     pO, pml, ab);

  hipLaunchKernelGGL((gemm_kernel<64, 128, true, false>), dim3(HID / 128, M_ROWS / 64),
                     dim3(256), 0, stream, ab, Wmixt, bmix, (void*)out, (short*)nullptr,
                     HID, DIN);
}